// Round 1
// baseline (802.851 us; speedup 1.0000x reference)
//
#include <hip/hip_runtime.h>
#include <hip/hip_bf16.h>

#define CDIV(a,b) (((a)+(b)-1)/(b))
#define BM 64
#define BN 64
#define BKK 32

__device__ __forceinline__ float gelu_exact(float x){
  return 0.5f * x * (1.0f + erff(x * 0.7071067811865475f));
}

// ---------------- CSR build ----------------
__global__ void k_clear_int(int* __restrict__ p, int n){
  int i = blockIdx.x*256 + threadIdx.x;
  if (i < n) p[i] = 0;
}

__global__ void k_deg(const int* __restrict__ dst, int* __restrict__ deg, int E){
  int e = blockIdx.x*256 + threadIdx.x;
  if (e < E) atomicAdd(&deg[dst[e]], 1);
}

// single-block chunked Hillis-Steele exclusive scan; N up to ~10M fine
__global__ void k_scan(const int* __restrict__ deg, int* __restrict__ row_ptr, int N){
  __shared__ int buf[1024];
  __shared__ int carry;
  if (threadIdx.x == 0) carry = 0;
  __syncthreads();
  int nch = (N + 1023) / 1024;
  for (int ch = 0; ch < nch; ++ch){
    int i = ch*1024 + threadIdx.x;
    int v = (i < N) ? deg[i] : 0;
    buf[threadIdx.x] = v;
    __syncthreads();
    #pragma unroll
    for (int off = 1; off < 1024; off <<= 1){
      int t = 0;
      if (threadIdx.x >= off) t = buf[threadIdx.x - off];
      __syncthreads();
      if (threadIdx.x >= off) buf[threadIdx.x] += t;
      __syncthreads();
    }
    if (i < N) row_ptr[i] = carry + buf[threadIdx.x] - v;  // exclusive
    int tot = buf[1023];
    __syncthreads();
    if (threadIdx.x == 0) carry += tot;
    __syncthreads();
  }
  if (threadIdx.x == 0) row_ptr[N] = carry;
}

__global__ void k_copy_int(const int* __restrict__ a, int* __restrict__ b, int n){
  int i = blockIdx.x*256 + threadIdx.x;
  if (i < n) b[i] = a[i];
}

__global__ void k_fill(const int* __restrict__ src, const int* __restrict__ dst,
                       int* __restrict__ cursor, int* __restrict__ srcs,
                       int* __restrict__ dsts, int E){
  int e = blockIdx.x*256 + threadIdx.x;
  if (e >= E) return;
  int d = dst[e];
  int pos = atomicAdd(&cursor[d], 1);
  srcs[pos] = src[e];
  dsts[pos] = d;
}

// -------- fold per-head relation matrix into projection weight --------
// Weff[c, h*32+e] = sum_d W[c, h*32+d] * A[h,d,e];  row 128 == bias row
__global__ void k_fuse_rel(const float* __restrict__ W, const float* __restrict__ b,
                           const float* __restrict__ A, float* __restrict__ Weff,
                           float* __restrict__ beff){
  int t = blockIdx.x*256 + threadIdx.x;
  if (t >= 129*128) return;
  int row = t >> 7;        // 0..128 (128 = bias)
  int col = t & 127;
  int h = col >> 5, e2 = col & 31;
  const float* s = (row < 128) ? (W + row*128 + h*32) : (b + h*32);
  const float* Ah = A + h*1024 + e2;     // A[h][d][e2], stride 32 over d
  float acc = 0.f;
  #pragma unroll
  for (int d = 0; d < 32; ++d) acc += s[d] * Ah[d*32];
  if (row < 128) Weff[row*128 + col] = acc;
  else           beff[col] = acc;
}

// ---------------- fp32 tiled GEMM: C = act(A) @ B + bias (+ skip-mix) ----------------
template<bool GELU_A, bool MIX>
__global__ __launch_bounds__(256)
void k_gemm(const float* __restrict__ A, const float* __restrict__ B,
            const float* __restrict__ bias, float* __restrict__ C,
            int M, int N, int K,
            const float* __restrict__ mixsrc, const float* __restrict__ skipp){
  __shared__ float As[BKK][BM+4];
  __shared__ float Bs[BKK][BN+4];
  const int tid = threadIdx.x;
  const int bm = blockIdx.y * BM;
  const int bn = blockIdx.x * BN;
  const int ty4 = (tid >> 4) * 4;
  const int tx4 = (tid & 15) * 4;
  const int ar  = tid >> 3;          // 0..31
  const int ac4 = (tid & 7) * 4;     // 0..28
  const int br  = tid >> 4;          // 0..15
  const int bc4 = (tid & 15) * 4;    // 0..60
  float acc[4][4] = {};
  for (int k0 = 0; k0 < K; k0 += BKK){
    #pragma unroll
    for (int rr = ar; rr < BM; rr += 32){
      float4 v = make_float4(0.f,0.f,0.f,0.f);
      if (bm + rr < M) v = *(const float4*)(A + (size_t)(bm+rr)*K + k0 + ac4);
      if (GELU_A){ v.x = gelu_exact(v.x); v.y = gelu_exact(v.y);
                   v.z = gelu_exact(v.z); v.w = gelu_exact(v.w); }
      As[ac4+0][rr] = v.x; As[ac4+1][rr] = v.y;
      As[ac4+2][rr] = v.z; As[ac4+3][rr] = v.w;
    }
    #pragma unroll
    for (int rr = br; rr < BKK; rr += 16){
      float4 v = *(const float4*)(B + (size_t)(k0+rr)*N + bn + bc4);
      *(float4*)&Bs[rr][bc4] = v;
    }
    __syncthreads();
    #pragma unroll
    for (int kk = 0; kk < BKK; ++kk){
      float4 av = *(const float4*)&As[kk][ty4];
      float4 bv = *(const float4*)&Bs[kk][tx4];
      float a_[4] = {av.x, av.y, av.z, av.w};
      float b_[4] = {bv.x, bv.y, bv.z, bv.w};
      #pragma unroll
      for (int i = 0; i < 4; ++i)
        #pragma unroll
        for (int j = 0; j < 4; ++j)
          acc[i][j] += a_[i] * b_[j];
    }
    __syncthreads();
  }
  float sg = 0.f;
  if (MIX) sg = 1.f / (1.f + expf(-skipp[0]));
  #pragma unroll
  for (int i = 0; i < 4; ++i){
    int r = bm + ty4 + i;
    if (r >= M) continue;
    #pragma unroll
    for (int j = 0; j < 4; ++j){
      int c = bn + tx4 + j;
      float o = acc[i][j] + bias[c];
      if (MIX) o = sg*o + (1.f - sg)*mixsrc[(size_t)r*N + c];
      C[(size_t)r*N + c] = o;
    }
  }
}

// ---------------- per-edge attention logits ----------------
// alpha[e,h] = (Q[dst]·K[src])_h * p[h] / sqrt(32)
__global__ void k_alpha(const float* __restrict__ Kb, const float* __restrict__ Qb,
                        const int* __restrict__ srcs, const int* __restrict__ dsts,
                        const float* __restrict__ p, float* __restrict__ alpha, int E){
  int t = blockIdx.x*256 + threadIdx.x;
  if (t >= E*4) return;
  int e = t >> 2, h = t & 3;
  int s = srcs[e], d = dsts[e];
  const float4* kv = (const float4*)(Kb + (size_t)s*128 + h*32);
  const float4* qv = (const float4*)(Qb + (size_t)d*128 + h*32);
  float acc = 0.f;
  #pragma unroll
  for (int i = 0; i < 8; ++i){
    float4 a = kv[i], b = qv[i];
    acc += a.x*b.x + a.y*b.y + a.z*b.z + a.w*b.w;
  }
  alpha[(size_t)e*4 + h] = acc * p[h] * 0.17677669529663687f;
}

// ---------------- segment softmax + weighted aggregation, one wave per node ----------------
__global__ __launch_bounds__(256)
void k_node(const float* __restrict__ alpha, const int* __restrict__ srcs,
            const int* __restrict__ row_ptr, const float* __restrict__ V,
            float* __restrict__ agg, int NN){
  int wave = threadIdx.x >> 6;
  int lane = threadIdx.x & 63;
  int node = blockIdx.x*4 + wave;
  if (node >= NN) return;
  int start = row_ptr[node], end = row_ptr[node+1];
  float* out = agg + (size_t)node*128;
  if (end == start){ out[lane] = 0.f; out[lane+64] = 0.f; return; }
  // pass 1: per-head max (strided over lanes, then wave reduce)
  float m0=-INFINITY, m1=-INFINITY, m2=-INFINITY, m3=-INFINITY;
  for (int j = start + lane; j < end; j += 64){
    float4 a = *(const float4*)(alpha + (size_t)j*4);
    m0 = fmaxf(m0, a.x); m1 = fmaxf(m1, a.y);
    m2 = fmaxf(m2, a.z); m3 = fmaxf(m3, a.w);
  }
  #pragma unroll
  for (int off = 32; off; off >>= 1){
    m0 = fmaxf(m0, __shfl_xor(m0, off));
    m1 = fmaxf(m1, __shfl_xor(m1, off));
    m2 = fmaxf(m2, __shfl_xor(m2, off));
    m3 = fmaxf(m3, __shfl_xor(m3, off));
  }
  // lane owns channels [lane] (head lane>>5) and [lane+64] (head 2+(lane>>5))
  int hsel = lane >> 5;
  float mA = hsel ? m1 : m0;
  float mB = hsel ? m3 : m2;
  float acc0 = 0.f, acc1 = 0.f, den0 = 0.f, den1 = 0.f;
  for (int j = start; j < end; ++j){
    float4 a = *(const float4*)(alpha + (size_t)j*4);   // broadcast
    float aA = hsel ? a.y : a.x;
    float aB = hsel ? a.w : a.z;
    float w0 = expf(aA - mA);
    float w1 = expf(aB - mB);
    den0 += w0; den1 += w1;
    int s = srcs[j];
    acc0 += w0 * V[(size_t)s*128 + lane];
    acc1 += w1 * V[(size_t)s*128 + 64 + lane];
  }
  out[lane]      = acc0 / den0;
  out[lane + 64] = acc1 / den1;
}

// ---------------- decoder ----------------
__global__ void k_gemv2(const float* __restrict__ z, const float* __restrict__ Wlp,
                        float* __restrict__ s1, float* __restrict__ s2, int NN){
  int n = blockIdx.x*256 + threadIdx.x;
  if (n >= NN) return;
  const float4* row = (const float4*)(z + (size_t)n*128);
  float a0 = 0.f, a1 = 0.f;
  #pragma unroll
  for (int i = 0; i < 32; ++i){
    float4 v  = row[i];
    float4 w1 = ((const float4*)Wlp)[i];
    float4 w2 = ((const float4*)Wlp)[32 + i];
    a0 += v.x*w1.x + v.y*w1.y + v.z*w1.z + v.w*w1.w;
    a1 += v.x*w2.x + v.y*w2.y + v.z*w2.z + v.w*w2.w;
  }
  s1[n] = a0; s2[n] = a1;
}

__global__ void k_decode(const int* __restrict__ pe, const int* __restrict__ ne,
                         const float* __restrict__ s1, const float* __restrict__ s2,
                         const float* __restrict__ blp, float* __restrict__ out, int P){
  int i = blockIdx.x*256 + threadIdx.x;
  if (i < P){
    out[i] = s1[pe[i]] + s2[pe[P + i]] + blp[0];
  } else if (i < 2*P){
    int j = i - P;
    out[P + j] = s1[ne[j]] + s2[ne[P + j]] + blp[0];
  }
}

extern "C" void kernel_launch(void* const* d_in, const int* in_sizes, int n_in,
                              void* d_out, int out_size, void* d_ws, size_t ws_size,
                              hipStream_t stream){
  const float* x      = (const float*)d_in[0];
  const int*   ei     = (const int*)d_in[1];
  const int*   pos_ei = (const int*)d_in[3];
  const int*   neg_ei = (const int*)d_in[4];
  const int NN = in_sizes[0] / 128;
  const int E  = in_sizes[1] / 2;
  const int P  = in_sizes[3] / 2;
  const int* e_src = ei;
  const int* e_dst = ei + E;

  char* wsb = (char*)d_ws;
  size_t off = 0;
  auto alloc = [&](size_t bytes)->char*{
    char* r = wsb + off;
    off = (off + bytes + 255) & ~(size_t)255;
    return r;
  };
  float* Kb     = (float*)alloc((size_t)NN*128*4);
  float* Qb     = (float*)alloc((size_t)NN*128*4);
  float* Vb     = (float*)alloc((size_t)NN*128*4);
  float* agg    = (float*)alloc((size_t)NN*128*4);
  float* h1     = (float*)alloc((size_t)NN*128*4);
  float* alphaB = (float*)alloc((size_t)E*4*4);
  int*   srcs   = (int*)alloc((size_t)E*4);
  int*   dsts   = (int*)alloc((size_t)E*4);
  int*   rowp   = (int*)alloc((size_t)(NN+1)*4);
  int*   deg    = (int*)alloc((size_t)NN*4);
  int*   cursor = (int*)alloc((size_t)NN*4);
  float* WeffK  = (float*)alloc(128*128*4);
  float* beffK  = (float*)alloc(128*4);
  float* WeffV  = (float*)alloc(128*128*4);
  float* beffV  = (float*)alloc(128*4);
  float* s1     = (float*)alloc((size_t)NN*4);
  float* s2     = (float*)alloc((size_t)NN*4);
  float* h2     = Kb;   // safe reuse: Kb dead after layer-2 alpha

  // ---- CSR (shared by both layers) ----
  k_clear_int<<<CDIV(NN,256),256,0,stream>>>(deg, NN);
  k_deg<<<CDIV(E,256),256,0,stream>>>(e_dst, deg, E);
  k_scan<<<1,1024,0,stream>>>(deg, rowp, NN);
  k_copy_int<<<CDIV(NN,256),256,0,stream>>>(rowp, cursor, NN);
  k_fill<<<CDIV(E,256),256,0,stream>>>(e_src, e_dst, cursor, srcs, dsts, E);

  dim3 ggrid(128/BN, CDIV(NN,BM));
  auto layer = [&](const float* hin, float* hout, int base){
    const float* Wk  = (const float*)d_in[base+0];
    const float* bk  = (const float*)d_in[base+1];
    const float* Wq  = (const float*)d_in[base+2];
    const float* bq  = (const float*)d_in[base+3];
    const float* Wv  = (const float*)d_in[base+4];
    const float* bv  = (const float*)d_in[base+5];
    const float* a   = (const float*)d_in[base+6];
    const float* m   = (const float*)d_in[base+7];
    const float* p   = (const float*)d_in[base+8];
    const float* Wo  = (const float*)d_in[base+9];
    const float* bo  = (const float*)d_in[base+10];
    const float* sk  = (const float*)d_in[base+11];
    k_fuse_rel<<<65,256,0,stream>>>(Wk, bk, a, WeffK, beffK);
    k_fuse_rel<<<65,256,0,stream>>>(Wv, bv, m, WeffV, beffV);
    k_gemm<false,false><<<ggrid,256,0,stream>>>(hin, WeffK, beffK, Kb, NN,128,128, nullptr, nullptr);
    k_gemm<false,false><<<ggrid,256,0,stream>>>(hin, Wq,    bq,    Qb, NN,128,128, nullptr, nullptr);
    k_gemm<false,false><<<ggrid,256,0,stream>>>(hin, WeffV, beffV, Vb, NN,128,128, nullptr, nullptr);
    k_alpha<<<CDIV(E*4,256),256,0,stream>>>(Kb, Qb, srcs, dsts, p, alphaB, E);
    k_node<<<CDIV(NN,4),256,0,stream>>>(alphaB, srcs, rowp, Vb, agg, NN);
    k_gemm<true,true><<<ggrid,256,0,stream>>>(agg, Wo, bo, hout, NN,128,128, hin, sk);
  };
  layer(x,  h1, 5);
  layer(h1, h2, 17);

  k_gemv2<<<CDIV(NN,256),256,0,stream>>>(h2, (const float*)d_in[29], s1, s2, NN);
  k_decode<<<CDIV(2*P,256),256,0,stream>>>(pos_ei, neg_ei, s1, s2,
                                           (const float*)d_in[30], (float*)d_out, P);
}